// Round 1
// baseline (1677.574 us; speedup 1.0000x reference)
//
#include <hip/hip_runtime.h>
#include <cstdint>
#include <cstddef>

// ---------------------------------------------------------------------------
// DPN_88965952569844: out = relu(x@W1^T + b1) -> concat(x,h1) @ W2^T + b2
// B=4096, D_IN=4096, HID=16384, OUT=1000.  fp32 in/out, bf16 MFMA compute.
// Structure: m97-style 128x128x32 NT GEMM, global_load_lds(16B), 4 waves 2x2.
// ---------------------------------------------------------------------------

using u16 = unsigned short;

typedef __bf16 bf16x8 __attribute__((ext_vector_type(8)));
typedef float  f32x4  __attribute__((ext_vector_type(4)));

#define BM 128
#define BN 128
#define BK 32

#define GLOBAL_AS __attribute__((address_space(1)))
#define LDS_AS    __attribute__((address_space(3)))

__device__ __forceinline__ void async_load16(const void* gp, void* lp) {
    __builtin_amdgcn_global_load_lds((GLOBAL_AS void*)gp, (LDS_AS void*)lp, 16, 0, 0);
}

__device__ __forceinline__ u16 f2bf(float f) {
    union { float f; uint32_t u; } c; c.f = f;
    uint32_t u = c.u;
    u += 0x7FFFu + ((u >> 16) & 1u);   // round-to-nearest-even
    return (u16)(u >> 16);
}

// ---------------------------------------------------------------------------
// fp32 -> bf16 conversion kernels
// ---------------------------------------------------------------------------

// x [4096][4096] fp32 -> dst rows stride 20480 (cols 0..4095 of concat)
__global__ void cvt_x_kernel(const float* __restrict__ x, u16* __restrict__ dst) {
    int idx = blockIdx.x * 256 + threadIdx.x;      // one thread per 4 elems
    int row = idx >> 10;                           // 1024 float4 per row
    int c4  = (idx & 1023) << 2;
    float4 v = *(const float4*)&x[(size_t)row * 4096 + c4];
    ushort4 o;
    o.x = f2bf(v.x); o.y = f2bf(v.y); o.z = f2bf(v.z); o.w = f2bf(v.w);
    *(ushort4*)&dst[(size_t)row * 20480 + c4] = o;
}

// flat contiguous convert (W1: 16384*4096 elems)
__global__ void cvt_flat_kernel(const float* __restrict__ src, u16* __restrict__ dst) {
    int idx = blockIdx.x * 256 + threadIdx.x;      // one thread per 4 elems
    float4 v = *(const float4*)&src[(size_t)idx * 4];
    ushort4 o;
    o.x = f2bf(v.x); o.y = f2bf(v.y); o.z = f2bf(v.z); o.w = f2bf(v.w);
    *(ushort4*)&dst[(size_t)idx * 4] = o;
}

// W2 [1000][20480] -> dst [1024][20480], rows 1000..1023 zero-filled
__global__ void cvt_w2_kernel(const float* __restrict__ src, u16* __restrict__ dst) {
    int idx = blockIdx.x * 256 + threadIdx.x;      // one thread per 4 elems
    int row = idx / 5120;                          // 20480/4 groups per row
    int c4  = (idx % 5120) * 4;
    ushort4 o;
    if (row < 1000) {
        float4 v = *(const float4*)&src[(size_t)row * 20480 + c4];
        o.x = f2bf(v.x); o.y = f2bf(v.y); o.z = f2bf(v.z); o.w = f2bf(v.w);
    } else {
        o.x = 0; o.y = 0; o.z = 0; o.w = 0;
    }
    *(ushort4*)&dst[(size_t)row * 20480 + c4] = o;
}

// ---------------------------------------------------------------------------
// NT bf16 GEMM: C[M,N] = A[M,K] * B[N,K]^T   (both K-contiguous)
// EPI 0: C = bf16(relu(acc + bias[n])), C is u16*, ldc elems
// EPI 1: C = fp32(acc + bias[n]) with n < Nmax guard, C is float*
// ---------------------------------------------------------------------------
template <int EPI>
__global__ __launch_bounds__(256, 2)
void gemm_bt_kernel(const u16* __restrict__ A, int lda,
                    const u16* __restrict__ B, int ldb,
                    int K,
                    const float* __restrict__ bias,
                    void* __restrict__ Cout, int ldc, int Nmax) {
    __shared__ __align__(16) u16 As[BM * BK];   // 8 KB
    __shared__ __align__(16) u16 Bs[BN * BK];   // 8 KB

    const int tid = threadIdx.x;
    const int m0  = blockIdx.y * BM;
    const int n0  = blockIdx.x * BN;

    // staging: each thread owns two 8-elem (16B) chunks of each tile.
    // LDS layout [row][k] row-major contiguous — exactly lane order for
    // global_load_lds (wave-uniform base + lane*16B).
    const int ea0 = tid * 8;        // elem offset chunk 0 (0..2040)
    const int ea1 = ea0 + 2048;     // elem offset chunk 1

    const u16* ag0 = A + (size_t)(m0 + (ea0 >> 5)) * lda + (ea0 & 31);
    const u16* ag1 = A + (size_t)(m0 + (ea1 >> 5)) * lda + (ea1 & 31);
    const u16* bg0 = B + (size_t)(n0 + (ea0 >> 5)) * ldb + (ea0 & 31);
    const u16* bg1 = B + (size_t)(n0 + (ea1 >> 5)) * ldb + (ea1 & 31);
    u16* al0 = &As[ea0];
    u16* al1 = &As[ea1];
    u16* bl0 = &Bs[ea0];
    u16* bl1 = &Bs[ea1];

    const int wave = tid >> 6;
    const int lane = tid & 63;
    const int wr   = (wave >> 1) * 64;   // wave row base in tile
    const int wc   = (wave & 1) * 64;    // wave col base in tile
    const int ln16 = lane & 15;
    const int quad = lane >> 4;

    f32x4 acc[4][4] = {};

    for (int k0 = 0; k0 < K; k0 += BK) {
        async_load16(ag0, al0);
        async_load16(ag1, al1);
        async_load16(bg0, bl0);
        async_load16(bg1, bl1);
        ag0 += BK; ag1 += BK; bg0 += BK; bg1 += BK;
        __syncthreads();   // drains vmcnt (global_load_lds) + barrier

        bf16x8 a[4], b[4];
#pragma unroll
        for (int i = 0; i < 4; ++i)
            a[i] = *(const bf16x8*)&As[(wr + i * 16 + ln16) * BK + quad * 8];
#pragma unroll
        for (int j = 0; j < 4; ++j)
            b[j] = *(const bf16x8*)&Bs[(wc + j * 16 + ln16) * BK + quad * 8];

#pragma unroll
        for (int i = 0; i < 4; ++i)
#pragma unroll
            for (int j = 0; j < 4; ++j)
                acc[i][j] = __builtin_amdgcn_mfma_f32_16x16x32_bf16(
                    a[i], b[j], acc[i][j], 0, 0, 0);

        __syncthreads();   // protect LDS from next iteration's staging
    }

    // epilogue: C/D layout col = lane&15, row = quad*4 + reg
    if (EPI == 0) {
        u16* C = (u16*)Cout;
#pragma unroll
        for (int i = 0; i < 4; ++i) {
#pragma unroll
            for (int j = 0; j < 4; ++j) {
                const int col = n0 + wc + j * 16 + ln16;
                const float bv = bias[col];
#pragma unroll
                for (int r = 0; r < 4; ++r) {
                    const int row = m0 + wr + i * 16 + quad * 4 + r;
                    float v = acc[i][j][r] + bv;
                    v = v > 0.0f ? v : 0.0f;
                    C[(size_t)row * ldc + col] = f2bf(v);
                }
            }
        }
    } else {
        float* C = (float*)Cout;
#pragma unroll
        for (int i = 0; i < 4; ++i) {
#pragma unroll
            for (int j = 0; j < 4; ++j) {
                const int col = n0 + wc + j * 16 + ln16;
                if (col < Nmax) {
                    const float bv = bias[col];
#pragma unroll
                    for (int r = 0; r < 4; ++r) {
                        const int row = m0 + wr + i * 16 + quad * 4 + r;
                        C[(size_t)row * ldc + col] = acc[i][j][r] + bv;
                    }
                }
            }
        }
    }
}

// ---------------------------------------------------------------------------

extern "C" void kernel_launch(void* const* d_in, const int* in_sizes, int n_in,
                              void* d_out, int out_size, void* d_ws, size_t ws_size,
                              hipStream_t stream) {
    const float* x  = (const float*)d_in[0];   // [4096, 4096]
    const float* W1 = (const float*)d_in[1];   // [16384, 4096]
    const float* b1 = (const float*)d_in[2];   // [16384]
    const float* W2 = (const float*)d_in[3];   // [1000, 20480]
    const float* b2 = (const float*)d_in[4];   // [1000]
    float* out = (float*)d_out;                // [4096, 1000]

    // workspace layout (bf16 elems)
    u16* concat = (u16*)d_ws;                        // [4096][20480]  167.8 MB
    u16* W1b = concat + (size_t)4096 * 20480;        // [16384][4096]  134.2 MB
    u16* W2b = W1b + (size_t)16384 * 4096;           // [1024][20480]   41.9 MB

    // conversions
    cvt_x_kernel   <<<16384, 256, 0, stream>>>(x, concat);   // 4096*1024 thr
    cvt_flat_kernel<<<65536, 256, 0, stream>>>(W1, W1b);     // 16777216 thr
    cvt_w2_kernel  <<<20480, 256, 0, stream>>>(W2, W2b);     // 5242880 thr

    // GEMM1: h1 = relu(x @ W1^T + b1) -> concat cols [4096, 20480)
    dim3 g1(16384 / BN, 4096 / BM);   // (128, 32)
    gemm_bt_kernel<0><<<g1, 256, 0, stream>>>(
        concat, 20480, W1b, 4096, 4096, b1, concat + 4096, 20480, 16384);

    // GEMM2: out = concat @ W2^T + b2   (N padded to 1024, store-guard 1000)
    dim3 g2(1024 / BN, 4096 / BM);    // (8, 32)
    gemm_bt_kernel<1><<<g2, 256, 0, stream>>>(
        concat, 20480, W2b, 20480, 20480, b2, out, 1000, 1000);
}

// Round 2
// 1451.758 us; speedup vs baseline: 1.1555x; 1.1555x over previous
//
#include <hip/hip_runtime.h>
#include <cstdint>
#include <cstddef>

// ---------------------------------------------------------------------------
// DPN_88965952569844: out = relu(x@W1^T + b1) -> concat(x,h1) @ W2^T + b2
// B=4096, D_IN=4096, HID=16384, OUT=1000.  fp32 in/out, bf16 MFMA compute.
// R2: + XOR-swizzled LDS chunks (bank-conflict-free ds_read_b128)
//     + split-K=4 GEMM2 (1024 blocks) with fp32 partials + reduce kernel.
// ---------------------------------------------------------------------------

using u16 = unsigned short;

typedef __bf16 bf16x8 __attribute__((ext_vector_type(8)));
typedef float  f32x4  __attribute__((ext_vector_type(4)));

#define BM 128
#define BN 128
#define BK 32

#define GLOBAL_AS __attribute__((address_space(1)))
#define LDS_AS    __attribute__((address_space(3)))

__device__ __forceinline__ void async_load16(const void* gp, void* lp) {
    __builtin_amdgcn_global_load_lds((GLOBAL_AS void*)gp, (LDS_AS void*)lp, 16, 0, 0);
}

__device__ __forceinline__ u16 f2bf(float f) {
    union { float f; uint32_t u; } c; c.f = f;
    uint32_t u = c.u;
    u += 0x7FFFu + ((u >> 16) & 1u);   // round-to-nearest-even
    return (u16)(u >> 16);
}

// swizzle: tile row r holds its 4 16B-chunks permuted: phys = q ^ ((r>>1)&3)
__device__ __forceinline__ int swz(int q, int row) { return q ^ ((row >> 1) & 3); }

// ---------------------------------------------------------------------------
// fp32 -> bf16 conversion kernels
// ---------------------------------------------------------------------------

__global__ void cvt_x_kernel(const float* __restrict__ x, u16* __restrict__ dst) {
    int idx = blockIdx.x * 256 + threadIdx.x;
    int row = idx >> 10;
    int c4  = (idx & 1023) << 2;
    float4 v = *(const float4*)&x[(size_t)row * 4096 + c4];
    ushort4 o;
    o.x = f2bf(v.x); o.y = f2bf(v.y); o.z = f2bf(v.z); o.w = f2bf(v.w);
    *(ushort4*)&dst[(size_t)row * 20480 + c4] = o;
}

__global__ void cvt_flat_kernel(const float* __restrict__ src, u16* __restrict__ dst) {
    int idx = blockIdx.x * 256 + threadIdx.x;
    float4 v = *(const float4*)&src[(size_t)idx * 4];
    ushort4 o;
    o.x = f2bf(v.x); o.y = f2bf(v.y); o.z = f2bf(v.z); o.w = f2bf(v.w);
    *(ushort4*)&dst[(size_t)idx * 4] = o;
}

__global__ void cvt_w2_kernel(const float* __restrict__ src, u16* __restrict__ dst) {
    int idx = blockIdx.x * 256 + threadIdx.x;
    int row = idx / 5120;
    int c4  = (idx % 5120) * 4;
    ushort4 o;
    if (row < 1000) {
        float4 v = *(const float4*)&src[(size_t)row * 20480 + c4];
        o.x = f2bf(v.x); o.y = f2bf(v.y); o.z = f2bf(v.z); o.w = f2bf(v.w);
    } else {
        o.x = 0; o.y = 0; o.z = 0; o.w = 0;
    }
    *(ushort4*)&dst[(size_t)row * 20480 + c4] = o;
}

// ---------------------------------------------------------------------------
// NT bf16 GEMM: C[M,N] = A[M,K'] * B[N,K']^T, K' = per-block K (blockIdx.z
// selects the K-chunk: A/B advanced by kz*K, C advanced by kz*c_slab).
// EPI 0: C = bf16(relu(acc + bias[n])), C is u16*
// EPI 1: C = fp32 raw partial (no bias), C is float*
// ---------------------------------------------------------------------------
template <int EPI>
__global__ __launch_bounds__(256, 2)
void gemm_bt_kernel(const u16* __restrict__ A, int lda,
                    const u16* __restrict__ B, int ldb,
                    int K,
                    const float* __restrict__ bias,
                    void* __restrict__ Cout, int ldc, size_t c_slab) {
    __shared__ __align__(16) u16 As[BM * BK];   // 8 KB
    __shared__ __align__(16) u16 Bs[BN * BK];   // 8 KB

    const int tid = threadIdx.x;
    const int m0  = blockIdx.y * BM;
    const int n0  = blockIdx.x * BN;
    const int kz  = blockIdx.z;

    A += (size_t)kz * K;
    B += (size_t)kz * K;

    // staging: thread owns 16B chunk c (and c+256). chunk c -> tile row c>>2,
    // physical slot c&3; it loads global k-chunk swz(c&3,row) of that row.
    const int r0 = tid >> 2;                 // chunk0 row (0..63)
    const int q0 = swz(tid & 3, r0);
    const int r1 = r0 + 64;                  // chunk1 row (64..127)
    const int q1 = swz(tid & 3, r1);

    const u16* ag0 = A + (size_t)(m0 + r0) * lda + q0 * 8;
    const u16* ag1 = A + (size_t)(m0 + r1) * lda + q1 * 8;
    const u16* bg0 = B + (size_t)(n0 + r0) * ldb + q0 * 8;
    const u16* bg1 = B + (size_t)(n0 + r1) * ldb + q1 * 8;
    u16* al0 = &As[tid * 8];
    u16* al1 = &As[tid * 8 + 2048];
    u16* bl0 = &Bs[tid * 8];
    u16* bl1 = &Bs[tid * 8 + 2048];

    const int wave = tid >> 6;
    const int lane = tid & 63;
    const int wr   = (wave >> 1) * 64;
    const int wc   = (wave & 1) * 64;
    const int ln16 = lane & 15;
    const int quad = lane >> 4;

    // loop-invariant swizzled LDS read offsets
    int aoff[4], boff[4];
#pragma unroll
    for (int i = 0; i < 4; ++i) {
        const int ra = wr + i * 16 + ln16;
        aoff[i] = ra * BK + swz(quad, ra) * 8;
        const int rb = wc + i * 16 + ln16;
        boff[i] = rb * BK + swz(quad, rb) * 8;
    }

    f32x4 acc[4][4] = {};

    for (int k0 = 0; k0 < K; k0 += BK) {
        async_load16(ag0, al0);
        async_load16(ag1, al1);
        async_load16(bg0, bl0);
        async_load16(bg1, bl1);
        ag0 += BK; ag1 += BK; bg0 += BK; bg1 += BK;
        __syncthreads();

        bf16x8 a[4], b[4];
#pragma unroll
        for (int i = 0; i < 4; ++i) a[i] = *(const bf16x8*)&As[aoff[i]];
#pragma unroll
        for (int j = 0; j < 4; ++j) b[j] = *(const bf16x8*)&Bs[boff[j]];

#pragma unroll
        for (int i = 0; i < 4; ++i)
#pragma unroll
            for (int j = 0; j < 4; ++j)
                acc[i][j] = __builtin_amdgcn_mfma_f32_16x16x32_bf16(
                    a[i], b[j], acc[i][j], 0, 0, 0);

        __syncthreads();
    }

    // epilogue: C/D layout col = lane&15, row = quad*4 + reg
    if (EPI == 0) {
        u16* C = (u16*)Cout;
#pragma unroll
        for (int i = 0; i < 4; ++i) {
#pragma unroll
            for (int j = 0; j < 4; ++j) {
                const int col = n0 + wc + j * 16 + ln16;
                const float bv = bias[col];
#pragma unroll
                for (int r = 0; r < 4; ++r) {
                    const int row = m0 + wr + i * 16 + quad * 4 + r;
                    float v = acc[i][j][r] + bv;
                    v = v > 0.0f ? v : 0.0f;
                    C[(size_t)row * ldc + col] = f2bf(v);
                }
            }
        }
    } else {
        float* C = (float*)Cout + (size_t)kz * c_slab;
#pragma unroll
        for (int i = 0; i < 4; ++i) {
#pragma unroll
            for (int j = 0; j < 4; ++j) {
                const int col = n0 + wc + j * 16 + ln16;
#pragma unroll
                for (int r = 0; r < 4; ++r) {
                    const int row = m0 + wr + i * 16 + quad * 4 + r;
                    C[(size_t)row * ldc + col] = acc[i][j][r];
                }
            }
        }
    }
}

// out[m][n] = b2[n] + sum_{kz<4} part[kz][m][n], n < 1000 (float4 over n)
__global__ void reduce_out_kernel(const float* __restrict__ part,
                                  const float* __restrict__ b2,
                                  float* __restrict__ out) {
    const int idx = blockIdx.x * 256 + threadIdx.x;   // 4096*250
    const int m  = idx / 250;
    const int n4 = (idx % 250) * 4;
    const size_t slab = (size_t)4096 * 1024;
    const size_t off = (size_t)m * 1024 + n4;
    float4 s  = *(const float4*)&part[off];
    float4 p1 = *(const float4*)&part[slab + off];
    float4 p2 = *(const float4*)&part[2 * slab + off];
    float4 p3 = *(const float4*)&part[3 * slab + off];
    float4 bv = *(const float4*)&b2[n4];
    s.x += p1.x + p2.x + p3.x + bv.x;
    s.y += p1.y + p2.y + p3.y + bv.y;
    s.z += p1.z + p2.z + p3.z + bv.z;
    s.w += p1.w + p2.w + p3.w + bv.w;
    *(float4*)&out[(size_t)m * 1000 + n4] = s;
}

// ---------------------------------------------------------------------------

extern "C" void kernel_launch(void* const* d_in, const int* in_sizes, int n_in,
                              void* d_out, int out_size, void* d_ws, size_t ws_size,
                              hipStream_t stream) {
    const float* x  = (const float*)d_in[0];   // [4096, 4096]
    const float* W1 = (const float*)d_in[1];   // [16384, 4096]
    const float* b1 = (const float*)d_in[2];   // [16384]
    const float* W2 = (const float*)d_in[3];   // [1000, 20480]
    const float* b2 = (const float*)d_in[4];   // [1000]
    float* out = (float*)d_out;                // [4096, 1000]

    // workspace layout (bf16 elems)
    u16* concat = (u16*)d_ws;                        // [4096][20480]  167.8 MB
    u16* W1b = concat + (size_t)4096 * 20480;        // [16384][4096]  134.2 MB
    u16* W2b = W1b + (size_t)16384 * 4096;           // [1024][20480]   41.9 MB
    // partials reuse W1b region (free after GEMM1): 4*4096*1024 fp32 = 67 MB
    float* partials = (float*)W1b;

    cvt_x_kernel   <<<16384, 256, 0, stream>>>(x, concat);
    cvt_flat_kernel<<<65536, 256, 0, stream>>>(W1, W1b);
    cvt_w2_kernel  <<<20480, 256, 0, stream>>>(W2, W2b);

    // GEMM1: h1 = relu(x @ W1^T + b1) -> concat cols [4096, 20480)
    dim3 g1(16384 / BN, 4096 / BM, 1);   // (128, 32, 1)
    gemm_bt_kernel<0><<<g1, 256, 0, stream>>>(
        concat, 20480, W1b, 4096, 4096, b1, concat + 4096, 20480, 0);

    // GEMM2 split-K=4: partials[kz] = concat[:, kz*5120:(kz+1)*5120] @ W2^T
    dim3 g2(1024 / BN, 4096 / BM, 4);    // (8, 32, 4)
    gemm_bt_kernel<1><<<g2, 256, 0, stream>>>(
        concat, 20480, W2b, 20480, 5120, nullptr, partials, 1024,
        (size_t)4096 * 1024);

    // out = b2 + sum partials
    reduce_out_kernel<<<4000, 256, 0, stream>>>(partials, b2, out);
}

// Round 3
// 1368.787 us; speedup vs baseline: 1.2256x; 1.0606x over previous
//
#include <hip/hip_runtime.h>
#include <cstdint>
#include <cstddef>

// ---------------------------------------------------------------------------
// DPN_88965952569844: out = relu(x@W1^T + b1) -> concat(x,h1) @ W2^T + b2
// B=4096, D_IN=4096, HID=16384, OUT=1000.  fp32 in/out, bf16 MFMA compute.
// R3: + panel swizzle on GEMM1 (4 n-tiles x 32 m-tiles per 128 consecutive
//       dispatch ids) so W1 streams from HBM once and staging loads hit L2/L3
//       -> shallower vmcnt(0) barrier drain.
//     (R2: XOR-swizzled LDS = 0 bank conflicts; split-K=4 GEMM2 + reduce.)
// ---------------------------------------------------------------------------

using u16 = unsigned short;

typedef __bf16 bf16x8 __attribute__((ext_vector_type(8)));
typedef float  f32x4  __attribute__((ext_vector_type(4)));

#define BM 128
#define BN 128
#define BK 32

#define GLOBAL_AS __attribute__((address_space(1)))
#define LDS_AS    __attribute__((address_space(3)))

__device__ __forceinline__ void async_load16(const void* gp, void* lp) {
    __builtin_amdgcn_global_load_lds((GLOBAL_AS void*)gp, (LDS_AS void*)lp, 16, 0, 0);
}

__device__ __forceinline__ u16 f2bf(float f) {
    union { float f; uint32_t u; } c; c.f = f;
    uint32_t u = c.u;
    u += 0x7FFFu + ((u >> 16) & 1u);   // round-to-nearest-even
    return (u16)(u >> 16);
}

// LDS swizzle: tile row r holds its 4 16B-chunks permuted: phys = q ^ ((r>>1)&3)
__device__ __forceinline__ int swz(int q, int row) { return q ^ ((row >> 1) & 3); }

// ---------------------------------------------------------------------------
// fp32 -> bf16 conversion kernels
// ---------------------------------------------------------------------------

__global__ void cvt_x_kernel(const float* __restrict__ x, u16* __restrict__ dst) {
    int idx = blockIdx.x * 256 + threadIdx.x;
    int row = idx >> 10;
    int c4  = (idx & 1023) << 2;
    float4 v = *(const float4*)&x[(size_t)row * 4096 + c4];
    ushort4 o;
    o.x = f2bf(v.x); o.y = f2bf(v.y); o.z = f2bf(v.z); o.w = f2bf(v.w);
    *(ushort4*)&dst[(size_t)row * 20480 + c4] = o;
}

__global__ void cvt_flat_kernel(const float* __restrict__ src, u16* __restrict__ dst) {
    int idx = blockIdx.x * 256 + threadIdx.x;
    float4 v = *(const float4*)&src[(size_t)idx * 4];
    ushort4 o;
    o.x = f2bf(v.x); o.y = f2bf(v.y); o.z = f2bf(v.z); o.w = f2bf(v.w);
    *(ushort4*)&dst[(size_t)idx * 4] = o;
}

__global__ void cvt_w2_kernel(const float* __restrict__ src, u16* __restrict__ dst) {
    int idx = blockIdx.x * 256 + threadIdx.x;
    int row = idx / 5120;
    int c4  = (idx % 5120) * 4;
    ushort4 o;
    if (row < 1000) {
        float4 v = *(const float4*)&src[(size_t)row * 20480 + c4];
        o.x = f2bf(v.x); o.y = f2bf(v.y); o.z = f2bf(v.z); o.w = f2bf(v.w);
    } else {
        o.x = 0; o.y = 0; o.z = 0; o.w = 0;
    }
    *(ushort4*)&dst[(size_t)row * 20480 + c4] = o;
}

// ---------------------------------------------------------------------------
// NT bf16 GEMM: C[M,N] = A[M,K'] * B[N,K']^T, K' = per-block K (blockIdx.z
// selects the K-chunk: A/B advanced by kz*K, C advanced by kz*c_slab).
// EPI 0: C = bf16(relu(acc + bias[n])), C is u16*
// EPI 1: C = fp32 raw partial (no bias), C is float*
// SWZ 1: remap dispatch-linear id -> panels of 4 n-tiles x 32 m-tiles so
//        co-resident blocks share a small B working set (L2-resident).
// ---------------------------------------------------------------------------
template <int EPI, int SWZ>
__global__ __launch_bounds__(256, 2)
void gemm_bt_kernel(const u16* __restrict__ A, int lda,
                    const u16* __restrict__ B, int ldb,
                    int K,
                    const float* __restrict__ bias,
                    void* __restrict__ Cout, int ldc, size_t c_slab) {
    __shared__ __align__(16) u16 As[BM * BK];   // 8 KB
    __shared__ __align__(16) u16 Bs[BN * BK];   // 8 KB

    const int tid = threadIdx.x;

    int bx = blockIdx.x, by = blockIdx.y;
    if (SWZ) {
        const int lin    = by * (int)gridDim.x + bx;  // dispatch order (x fastest)
        const int panel  = lin >> 7;                  // 128 blocks / panel
        const int within = lin & 127;
        bx = panel * 4 + (within >> 5);               // n-tile: 4 per panel
        by = within & 31;                             // m-tile: all 32 per panel
    }
    const int m0 = by * BM;
    const int n0 = bx * BN;
    const int kz = blockIdx.z;

    A += (size_t)kz * K;
    B += (size_t)kz * K;

    // staging: thread owns 16B chunk c (and c+256). chunk c -> tile row c>>2,
    // physical slot c&3; it loads global k-chunk swz(c&3,row) of that row.
    const int r0 = tid >> 2;                 // chunk0 row (0..63)
    const int q0 = swz(tid & 3, r0);
    const int r1 = r0 + 64;                  // chunk1 row (64..127)
    const int q1 = swz(tid & 3, r1);

    const u16* ag0 = A + (size_t)(m0 + r0) * lda + q0 * 8;
    const u16* ag1 = A + (size_t)(m0 + r1) * lda + q1 * 8;
    const u16* bg0 = B + (size_t)(n0 + r0) * ldb + q0 * 8;
    const u16* bg1 = B + (size_t)(n0 + r1) * ldb + q1 * 8;
    u16* al0 = &As[tid * 8];
    u16* al1 = &As[tid * 8 + 2048];
    u16* bl0 = &Bs[tid * 8];
    u16* bl1 = &Bs[tid * 8 + 2048];

    const int wave = tid >> 6;
    const int lane = tid & 63;
    const int wr   = (wave >> 1) * 64;
    const int wc   = (wave & 1) * 64;
    const int ln16 = lane & 15;
    const int quad = lane >> 4;

    // loop-invariant swizzled LDS read offsets
    int aoff[4], boff[4];
#pragma unroll
    for (int i = 0; i < 4; ++i) {
        const int ra = wr + i * 16 + ln16;
        aoff[i] = ra * BK + swz(quad, ra) * 8;
        const int rb = wc + i * 16 + ln16;
        boff[i] = rb * BK + swz(quad, rb) * 8;
    }

    f32x4 acc[4][4] = {};

    for (int k0 = 0; k0 < K; k0 += BK) {
        async_load16(ag0, al0);
        async_load16(ag1, al1);
        async_load16(bg0, bl0);
        async_load16(bg1, bl1);
        ag0 += BK; ag1 += BK; bg0 += BK; bg1 += BK;
        __syncthreads();

        bf16x8 a[4], b[4];
#pragma unroll
        for (int i = 0; i < 4; ++i) a[i] = *(const bf16x8*)&As[aoff[i]];
#pragma unroll
        for (int j = 0; j < 4; ++j) b[j] = *(const bf16x8*)&Bs[boff[j]];

#pragma unroll
        for (int i = 0; i < 4; ++i)
#pragma unroll
            for (int j = 0; j < 4; ++j)
                acc[i][j] = __builtin_amdgcn_mfma_f32_16x16x32_bf16(
                    a[i], b[j], acc[i][j], 0, 0, 0);

        __syncthreads();
    }

    // epilogue: C/D layout col = lane&15, row = quad*4 + reg
    if (EPI == 0) {
        u16* C = (u16*)Cout;
#pragma unroll
        for (int i = 0; i < 4; ++i) {
#pragma unroll
            for (int j = 0; j < 4; ++j) {
                const int col = n0 + wc + j * 16 + ln16;
                const float bv = bias[col];
#pragma unroll
                for (int r = 0; r < 4; ++r) {
                    const int row = m0 + wr + i * 16 + quad * 4 + r;
                    float v = acc[i][j][r] + bv;
                    v = v > 0.0f ? v : 0.0f;
                    C[(size_t)row * ldc + col] = f2bf(v);
                }
            }
        }
    } else {
        float* C = (float*)Cout + (size_t)kz * c_slab;
#pragma unroll
        for (int i = 0; i < 4; ++i) {
#pragma unroll
            for (int j = 0; j < 4; ++j) {
                const int col = n0 + wc + j * 16 + ln16;
#pragma unroll
                for (int r = 0; r < 4; ++r) {
                    const int row = m0 + wr + i * 16 + quad * 4 + r;
                    C[(size_t)row * ldc + col] = acc[i][j][r];
                }
            }
        }
    }
}

// out[m][n] = b2[n] + sum_{kz<4} part[kz][m][n], n < 1000 (float4 over n)
__global__ void reduce_out_kernel(const float* __restrict__ part,
                                  const float* __restrict__ b2,
                                  float* __restrict__ out) {
    const int idx = blockIdx.x * 256 + threadIdx.x;   // 4096*250
    const int m  = idx / 250;
    const int n4 = (idx % 250) * 4;
    const size_t slab = (size_t)4096 * 1024;
    const size_t off = (size_t)m * 1024 + n4;
    float4 s  = *(const float4*)&part[off];
    float4 p1 = *(const float4*)&part[slab + off];
    float4 p2 = *(const float4*)&part[2 * slab + off];
    float4 p3 = *(const float4*)&part[3 * slab + off];
    float4 bv = *(const float4*)&b2[n4];
    s.x += p1.x + p2.x + p3.x + bv.x;
    s.y += p1.y + p2.y + p3.y + bv.y;
    s.z += p1.z + p2.z + p3.z + bv.z;
    s.w += p1.w + p2.w + p3.w + bv.w;
    *(float4*)&out[(size_t)m * 1000 + n4] = s;
}

// ---------------------------------------------------------------------------

extern "C" void kernel_launch(void* const* d_in, const int* in_sizes, int n_in,
                              void* d_out, int out_size, void* d_ws, size_t ws_size,
                              hipStream_t stream) {
    const float* x  = (const float*)d_in[0];   // [4096, 4096]
    const float* W1 = (const float*)d_in[1];   // [16384, 4096]
    const float* b1 = (const float*)d_in[2];   // [16384]
    const float* W2 = (const float*)d_in[3];   // [1000, 20480]
    const float* b2 = (const float*)d_in[4];   // [1000]
    float* out = (float*)d_out;                // [4096, 1000]

    // workspace layout (bf16 elems)
    u16* concat = (u16*)d_ws;                        // [4096][20480]  167.8 MB
    u16* W1b = concat + (size_t)4096 * 20480;        // [16384][4096]  134.2 MB
    u16* W2b = W1b + (size_t)16384 * 4096;           // [1024][20480]   41.9 MB
    // partials reuse W1b region (free after GEMM1): 4*4096*1024 fp32 = 67 MB
    float* partials = (float*)W1b;

    cvt_x_kernel   <<<16384, 256, 0, stream>>>(x, concat);
    cvt_flat_kernel<<<65536, 256, 0, stream>>>(W1, W1b);
    cvt_w2_kernel  <<<20480, 256, 0, stream>>>(W2, W2b);

    // GEMM1: h1 = relu(x @ W1^T + b1) -> concat cols [4096, 20480), swizzled
    dim3 g1(16384 / BN, 4096 / BM, 1);   // (128, 32, 1)
    gemm_bt_kernel<0, 1><<<g1, 256, 0, stream>>>(
        concat, 20480, W1b, 4096, 4096, b1, concat + 4096, 20480, 0);

    // GEMM2 split-K=4: partials[kz] = concat[:, kz*5120:(kz+1)*5120] @ W2^T
    dim3 g2(1024 / BN, 4096 / BM, 4);    // (8, 32, 4)
    gemm_bt_kernel<1, 0><<<g2, 256, 0, stream>>>(
        concat, 20480, W2b, 20480, 5120, nullptr, partials, 1024,
        (size_t)4096 * 1024);

    // out = b2 + sum partials
    reduce_out_kernel<<<4000, 256, 0, stream>>>(partials, b2, out);
}